// Round 9
// baseline (792.230 us; speedup 1.0000x reference)
//
#include <hip/hip_runtime.h>
#include <math.h>

#define NB 4
#define SS 16
#define NN 1024        // H*W

typedef short s8v __attribute__((ext_vector_type(8)));    // 8 bf16 (4 VGPR)
typedef float f4v __attribute__((ext_vector_type(4)));    // MFMA accumulator

__device__ __forceinline__ float sigm(float x) {
  return 1.0f / (1.0f + __expf(-x));
}
__device__ __forceinline__ float tanh_f(float x) {
  float e = __expf(2.0f * x);
  return 1.0f - 2.0f / (1.0f + e);
}
__device__ __forceinline__ unsigned short bf16r(float x) {   // RNE float->bf16
  unsigned int u = __float_as_uint(x);
  u = (u + 0x7FFFu + ((u >> 16) & 1u)) >> 16;
  return (unsigned short)u;
}
__device__ __forceinline__ float bf16f(unsigned short h) {
  return __uint_as_float(((unsigned int)h) << 16);
}

// ---------- prep: conv-weight split/pack + transposes + zero states ----------
__global__ void k0_prep(const float* __restrict__ conv_w, const float* __restrict__ z_w,
                        const float* __restrict__ m_w,
                        unsigned short* __restrict__ Whi, unsigned short* __restrict__ Wlo,
                        float* __restrict__ z_wT, float* __restrict__ m_wT,
                        float* __restrict__ h_A, float* __restrict__ c_st) {
  int stride = gridDim.x * blockDim.x;
  int i0 = blockIdx.x * blockDim.x + threadIdx.x;
  for (int i = i0; i < 256*1152; i += stride) {
    int oc = i / 1152, k = i - oc*1152;          // k = icComb*9 + ky*3 + kx
    float v = conv_w[i];
    unsigned short hi = bf16r(v);
    unsigned short lo = bf16r(v - bf16f(hi));
    int mt = oc >> 4, i16 = oc & 15;
    int ks = k >> 5, kk = k & 31;
    int lane = i16 | ((kk >> 3) << 4);
    int pos = ((mt*36 + ks)*64 + lane)*8 + (kk & 7);
    Whi[pos] = hi;
    Wlo[pos] = lo;
  }
  for (int i = i0; i < 128*128; i += stride) {
    int oc = i >> 7, k = i & 127;
    z_wT[k*128 + oc] = z_w[i];
  }
  for (int i = i0; i < 192*192; i += stride) {
    int oc = i / 192, k = i - oc*192;
    m_wT[k*192 + oc] = m_w[i];
  }
  for (int i = i0; i < NB*64*NN; i += stride) { h_A[i] = 0.0f; c_st[i] = 0.0f; }
}

// ---------- K0b v2: conv_x for ALL (b,t). N=64/block, K-split waves, gather im2col ----
// block = (b, t, y2) covering output rows y0=2*y2, y0+1. grid 1024.
__global__ __launch_bounds__(1024, 4) void k0b_gx(
    const float* __restrict__ X,
    const unsigned short* __restrict__ Whi, const unsigned short* __restrict__ Wlo,
    float* __restrict__ gx)
{
  // B-frags: [plane][seg = ks*4 + nt][lane][8]  = 2 * 73728 B = 147456 B
  __shared__ __align__(16) unsigned short Bfrag[2][18*4*64*8];
  float* gred = (float*)&Bfrag[0][0];            // alias after MFMA: [256][66] = 67.6 KB

  const int tid = threadIdx.x;
  const int bid = blockIdx.x;         // ((b*16 + t)*16 + y2)
  const int y2 = bid & 15;
  const int t  = (bid >> 4) & 15;
  const int b  = bid >> 8;
  const int y0 = y2 * 2;

  const float* Xs = X + (((long)b*64)*SS + t)*NN;   // + ic*(SS*NN) + gy*32 + gx

  // ---- phase 1: gather im2col -> conflict-free b128 LDS writes ----
  #pragma unroll
  for (int it = 0; it < 5; it++) {
    int slot = tid + it*1024;
    if (slot < 4608) {                 // 72 segs x 64 lanes
      int lane = slot & 63;
      int seg  = slot >> 6;            // ks*4 + nt
      int ks   = seg >> 2;
      int nt   = seg & 3;
      int n16  = lane & 15;
      int kk8  = lane >> 4;
      int n    = nt*16 + n16;          // 0..63
      int r    = n >> 5;               // output row within block
      int x    = n & 31;
      s8v hi8, lo8;
      #pragma unroll
      for (int j = 0; j < 8; j++) {
        int k  = ks*32 + kk8*8 + j;    // 0..575 (x-channel region)
        int ic = k / 9;
        int r9 = k - ic*9;
        int dy = r9 / 3;
        int dx = r9 - dy*3;
        int gy = y0 + r + dy - 1;
        int gxc = x + dx - 1;
        float v = 0.0f;
        if ((unsigned)gy < 32u && (unsigned)gxc < 32u)
          v = Xs[ic*(SS*NN) + gy*32 + gxc];
        unsigned short h = bf16r(v);
        hi8[j] = (short)h;
        lo8[j] = (short)bf16r(v - bf16f(h));
      }
      ((s8v*)&Bfrag[0][0])[seg*64 + lane] = hi8;
      ((s8v*)&Bfrag[1][0])[seg*64 + lane] = lo8;
    }
  }
  __syncthreads();

  // ---- phase 2: MFMA. wave = (mtp 0..7, kh 0..1): 2 m-tiles x 4 nt x 9 ks ----
  const int lane = tid & 63;
  const int wv   = tid >> 6;
  const int mtp  = wv >> 1;
  const int kh   = wv & 1;
  f4v acc[2][4];
  #pragma unroll
  for (int mi = 0; mi < 2; mi++)
    #pragma unroll
    for (int nt = 0; nt < 4; nt++)
      acc[mi][nt] = (f4v){0.f, 0.f, 0.f, 0.f};

  {
    const s8v* Bh = (const s8v*)&Bfrag[0][0] + lane;
    const s8v* Bl = (const s8v*)&Bfrag[1][0] + lane;
    const s8v* AH = (const s8v*)Whi + lane;
    const s8v* AL = (const s8v*)Wlo + lane;
    const int mt0 = mtp*2, mt1 = mt0 + 1;
    #pragma unroll 3
    for (int ks9 = 0; ks9 < 9; ks9++) {
      const int ks = kh*9 + ks9;
      s8v ah0 = AH[(mt0*36 + ks)*64];
      s8v al0 = AL[(mt0*36 + ks)*64];
      s8v ah1 = AH[(mt1*36 + ks)*64];
      s8v al1 = AL[(mt1*36 + ks)*64];
      #pragma unroll
      for (int nt = 0; nt < 4; nt++) {
        s8v bh = Bh[(ks*4 + nt)*64];
        s8v bl = Bl[(ks*4 + nt)*64];
        acc[0][nt] = __builtin_amdgcn_mfma_f32_16x16x32_bf16(ah0, bh, acc[0][nt], 0, 0, 0);
        acc[0][nt] = __builtin_amdgcn_mfma_f32_16x16x32_bf16(al0, bh, acc[0][nt], 0, 0, 0);
        acc[0][nt] = __builtin_amdgcn_mfma_f32_16x16x32_bf16(ah0, bl, acc[0][nt], 0, 0, 0);
        acc[1][nt] = __builtin_amdgcn_mfma_f32_16x16x32_bf16(ah1, bh, acc[1][nt], 0, 0, 0);
        acc[1][nt] = __builtin_amdgcn_mfma_f32_16x16x32_bf16(al1, bh, acc[1][nt], 0, 0, 0);
        acc[1][nt] = __builtin_amdgcn_mfma_f32_16x16x32_bf16(ah1, bl, acc[1][nt], 0, 0, 0);
      }
    }
  }
  __syncthreads();   // all B reads done; gred may alias Bfrag[0]

  // ---- phase 3: reduce K-halves via LDS, write gx coalesced ----
  const int c16 = lane & 15;
  const int rb  = (lane >> 4) * 4;
  if (kh == 0) {
    #pragma unroll
    for (int mi = 0; mi < 2; mi++)
      #pragma unroll
      for (int nt = 0; nt < 4; nt++)
        #pragma unroll
        for (int r = 0; r < 4; r++)
          gred[((mtp*2 + mi)*16 + rb + r)*66 + nt*16 + c16] = acc[mi][nt][r];
  }
  __syncthreads();
  if (kh == 1) {
    #pragma unroll
    for (int mi = 0; mi < 2; mi++)
      #pragma unroll
      for (int nt = 0; nt < 4; nt++)
        #pragma unroll
        for (int r = 0; r < 4; r++)
          gred[((mtp*2 + mi)*16 + rb + r)*66 + nt*16 + c16] += acc[mi][nt][r];
  }
  __syncthreads();
  {
    float* gout = gx + (((long)b*SS + t)*256)*NN + y0*32;
    #pragma unroll
    for (int it = 0; it < 16; it++) {
      int idx = tid + it*1024;
      int oc = idx >> 6, col = idx & 63;
      gout[oc*NN + col] = gred[oc*66 + col];
    }
  }
}

// ---------- K1: conv_h (MFMA split-bf16) + LSTM(+gx) + projections (1024 threads) ----------
__global__ __launch_bounds__(1024, 2) void k1_conv_lstm_proj(
    int t,
    const float* __restrict__ gx,
    const unsigned short* __restrict__ Whi, const unsigned short* __restrict__ Wlo,
    const float* __restrict__ conv_b,
    const float* __restrict__ W_ci, const float* __restrict__ W_cf, const float* __restrict__ W_co,
    const float* __restrict__ qw, const float* __restrict__ qb,
    const float* __restrict__ kw, const float* __restrict__ kb,
    const float* __restrict__ k2w, const float* __restrict__ k2b,
    const float* __restrict__ vw, const float* __restrict__ vb,
    const float* __restrict__ v2w, const float* __restrict__ v2b,
    const float* __restrict__ h_cur, float* __restrict__ h_nxt,
    float* __restrict__ c_st,
    float* __restrict__ q_buf,
    unsigned short* __restrict__ kF,
    unsigned short* __restrict__ vFh, unsigned short* __restrict__ vFl)
{
  __shared__ __align__(16) unsigned short Ihi_l[18*64*8];      // h-only im2col, B-frag order
  __shared__ __align__(16) unsigned short Ilo_l[18*64*8];
  __shared__ __align__(16) float gates_l[256*17];              // [oc][x]; later proj_l[176][16]
  __shared__ __align__(16) float h_l[16*68];                   // [x][c]
  __shared__ __align__(16) float c_l[16*68];

  const int tid = threadIdx.x;
  const int bid = blockIdx.x;
  const int b  = bid >> 6;
  const int y  = (bid >> 1) & 31;
  const int x0 = (bid & 1) * 16;
  const int mt = bid & 63;          // this block's 16-col m-tile (= n>>4)
  const int n0 = y*32 + x0;

  // ---- phase 0: h-only im2col -> bf16 hi/lo B-frags (local ks 0..17) ----
  for (int idx = tid; idx < 64*3*18; idx += 1024) {
    int col = idx % 18;
    int rest = idx / 18;
    int dy = rest % 3;
    int ic = rest / 3;                    // h channel 0..63
    int gy = y + dy - 1;
    int gxc = x0 + col - 1;
    float v = 0.0f;
    if ((unsigned)gy < 32u && (unsigned)gxc < 32u)
      v = h_cur[((b*64 + ic)*NN) + gy*32 + gxc];
    unsigned short hi = bf16r(v);
    unsigned short lo = bf16r(v - bf16f(hi));
    int kbase = ic*9 + dy*3;              // local k in [0,576)
    #pragma unroll
    for (int dx = 0; dx < 3; dx++) {
      int n = col - dx;
      if ((unsigned)n < 16u) {
        int k = kbase + dx;
        int ks = k >> 5, kk = k & 31;
        int pos = (ks*64 + (n | ((kk >> 3) << 4)))*8 + (kk & 7);
        Ihi_l[pos] = hi;
        Ilo_l[pos] = lo;
      }
    }
  }
  __syncthreads();

  // ---- phase 1: conv_h MFMA: 16 waves, 1 m-tile each; A-frags at ks 18..35 ----
  {
    const int lane = tid & 63;
    const int wv   = tid >> 6;        // 0..15 = m-tile
    f4v acc = {0.f, 0.f, 0.f, 0.f};
    const s8v* Ah = (const s8v*)Whi + (wv*36 + 18)*64 + lane;
    const s8v* Al = (const s8v*)Wlo + (wv*36 + 18)*64 + lane;
    const s8v* Bh = (const s8v*)Ihi_l + lane;
    const s8v* Bl = (const s8v*)Ilo_l + lane;
    #pragma unroll 3
    for (int ks = 0; ks < 18; ks++) {
      s8v ah = Ah[ks*64];
      s8v al = Al[ks*64];
      s8v bh = Bh[ks*64];
      s8v bl = Bl[ks*64];
      acc = __builtin_amdgcn_mfma_f32_16x16x32_bf16(ah, bh, acc, 0, 0, 0);
      acc = __builtin_amdgcn_mfma_f32_16x16x32_bf16(al, bh, acc, 0, 0, 0);
      acc = __builtin_amdgcn_mfma_f32_16x16x32_bf16(ah, bl, acc, 0, 0, 0);
    }
    const int colx = lane & 15;
    const int rb   = (lane >> 4) * 4;
    #pragma unroll
    for (int r = 0; r < 4; r++)
      gates_l[(wv*16 + rb + r)*17 + colx] = acc[r];
  }
  __syncthreads();

  // ---- phase 2: LSTM elementwise (adds precomputed gx) ----
  {
    const int x = tid & 15;
    const int c = tid >> 4;      // 0..63
    const int n = n0 + x;
    const float* gxp = gx + (((long)b*SS + t)*256)*NN + n;
    float ig = gates_l[(c      )*17 + x] + gxp[(c      )*NN] + conv_b[c];
    float fg = gates_l[( 64 + c)*17 + x] + gxp[( 64 + c)*NN] + conv_b[ 64 + c];
    float gg = gates_l[(128 + c)*17 + x] + gxp[(128 + c)*NN] + conv_b[128 + c];
    float og = gates_l[(192 + c)*17 + x] + gxp[(192 + c)*NN] + conv_b[192 + c];
    float cp = c_st[(b*64 + c)*NN + n];
    float i_ = sigm(ig + W_ci[c*NN + n] * cp);
    float f_ = sigm(fg + W_cf[c*NN + n] * cp);
    float cn = f_*cp + i_*tanh_f(gg);
    float o_ = sigm(og + W_co[c*NN + n] * cn);
    float hn = o_*tanh_f(cn);
    h_nxt[(b*64 + c)*NN + n] = hn;
    c_st[(b*64 + c)*NN + n] = cn;
    h_l[x*68 + c] = hn;
    c_l[x*68 + c] = cn;
  }
  __syncthreads();

  // ---- phase 3: projections -> LDS staging (proj_l aliases gates_l) ----
  float* proj_l = gates_l;
  #pragma unroll
  for (int r0 = 0; r0 < 3; r0++) {
    int task = tid + r0*1024;
    if (task < 176*16) {
      int po = task >> 4, x = task & 15;
      const float* src = (po < 96) ? &h_l[x*68] : &c_l[x*68];
      const float* w; float bias;
      if (po < 16)       { w = qw  + po*64;        bias = qb[po]; }
      else if (po < 32)  { w = kw  + (po-16)*64;   bias = kb[po-16]; }
      else if (po < 96)  { w = vw  + (po-32)*64;   bias = vb[po-32]; }
      else if (po < 112) { w = k2w + (po-96)*64;   bias = k2b[po-96]; }
      else               { w = v2w + (po-112)*64;  bias = v2b[po-112]; }
      float s = bias;
      #pragma unroll
      for (int k = 0; k < 64; k += 4) {
        float4 wv = *(const float4*)&w[k];
        float4 sv = *(const float4*)&src[k];
        s = fmaf(wv.x, sv.x, s); s = fmaf(wv.y, sv.y, s);
        s = fmaf(wv.z, sv.z, s); s = fmaf(wv.w, sv.w, s);
      }
      proj_l[po*16 + x] = s;
    }
  }
  __syncthreads();

  // ---- phase 4: coalesced fragment emission ----
  if (tid < 256) {
    int d = tid >> 4, x = tid & 15;
    q_buf[(b*16 + d)*NN + n0 + x] = proj_l[d*16 + x];
  }
  if (tid < 512) {
    int brh2 = tid >> 8;            // branch
    int lh   = (tid >> 2) & 63;     // fragment "lane-half" row
    int j2   = tid & 3;             // packs d&7 = 2*j2, 2*j2+1
    int p    = lh >> 4;             // 0,1: hi planes; 2,3: lo planes
    int x    = lh & 15;
    int d0   = ((p & 1) << 3) | (j2 << 1);
    int Koff = brh2 ? 96 : 16;
    float v0 = proj_l[(Koff + d0)*16 + x];
    float v1 = proj_l[(Koff + d0 + 1)*16 + x];
    unsigned short h0 = bf16r(v0), h1 = bf16r(v1);
    unsigned short u0, u1;
    if (p < 2) { u0 = h0; u1 = h1; }
    else       { u0 = bf16r(v0 - bf16f(h0)); u1 = bf16r(v1 - bf16f(h1)); }
    unsigned int* dst = (unsigned int*)(kF + ((b*2 + brh2)*64 + mt)*512);
    dst[lh*4 + j2] = (unsigned)u0 | ((unsigned)u1 << 16);
  }
  {
    const int ks = y;
    const int g0 = x0 >> 3;         // 0 or 2
    #pragma unroll
    for (int it = 0; it < 2; it++) {
      int ct    = tid + it*1024;
      int plane = ct >> 10;         // 0 = vFh, 1 = vFl
      int brh2  = (ct >> 9) & 1;
      int nt    = (ct >> 7) & 3;
      int li    = (ct >> 2) & 31;
      int j2    = ct & 3;
      int lane2 = g0*16 + li;
      int cch   = nt*16 + (lane2 & 15);
      int xx    = ((li >> 4) << 3) | (j2 << 1);
      int Voff  = brh2 ? 112 : 32;
      float v0 = proj_l[(Voff + cch)*16 + xx];
      float v1 = proj_l[(Voff + cch)*16 + xx + 1];
      unsigned short h0 = bf16r(v0), h1 = bf16r(v1);
      unsigned short u0, u1;
      if (plane == 0) { u0 = h0; u1 = h1; }
      else            { u0 = bf16r(v0 - bf16f(h0)); u1 = bf16r(v1 - bf16f(h1)); }
      unsigned short* basep = (plane ? vFl : vFh) + (((b*2 + brh2)*32 + ks)*4 + nt)*512;
      ((unsigned int*)basep)[lane2*4 + j2] = (unsigned)u0 | ((unsigned)u1 << 16);
    }
  }
}

// ---------- K2: dual attention via MFMA + combine + gating ----------
#define RED_OFF 0        // [16 waves][16 nl][66]  = 16896
#define PS_OFF  16896    // [16 waves][16][36]     = 9216
#define SMX_OFF 26112    // [2][8][16]             = 256
#define SSM_OFF 26368    // [2][8][16]             = 256
#define INV_OFF 26624    // [2][16]                = 32
#define ZHM_OFF 26656    // [128][16]              = 2048
#define S_TOT   28704

__global__ __launch_bounds__(1024, 4) void k2_attn(
    int t,
    const float* __restrict__ q_buf,
    const unsigned short* __restrict__ kF,
    const unsigned short* __restrict__ vFh, const unsigned short* __restrict__ vFl,
    float* __restrict__ h_nxt, float* __restrict__ c_st,
    const float* __restrict__ z_wT, const float* __restrict__ z_b,
    const float* __restrict__ m_wT, const float* __restrict__ m_b,
    float* __restrict__ out)
{
  __shared__ __align__(16) float S[S_TOT];
  float* red  = S + RED_OFF;
  float* smMax= S + SMX_OFF;
  float* smSum= S + SSM_OFF;
  float* invL = S + INV_OFF;
  float* zhm  = S + ZHM_OFF;
  float* cbIn = S;              // alias red (after barrier)
  float* cbOut= S + 3072;       // alias red

  const int tid = threadIdx.x;
  const int bid = blockIdx.x;
  const int xcd = bid & 7;
  const int b = xcd >> 1;
  const int tile = ((bid >> 3) << 1) | (xcd & 1);   // 0..63
  const int n0 = tile * 16;

  const int wid  = tid >> 6;
  const int lane = tid & 63;
  const int brh  = wid >> 3;      // branch
  const int w    = wid & 7;       // wave within branch
  const int g    = lane >> 4;
  const int c16  = lane & 15;

  // ---- Q A-frags: A1 = [Qh|Qh], A2 = [Ql|0] ----
  s8v qh1, ql2;
  {
    const int dbase = (g & 1) * 8;
    #pragma unroll
    for (int j = 0; j < 8; j++) {
      float qv = q_buf[(b*16 + dbase + j)*NN + n0 + c16];
      unsigned short hi = bf16r(qv);
      unsigned short lo = bf16r(qv - bf16f(hi));
      qh1[j] = (short)hi;
      ql2[j] = (g < 2) ? (short)lo : (short)0;
    }
  }

  // ---- scores: 8 m-tiles per wave, 2 MFMA each (B = [Kh|Kl]) ----
  f4v acc[8];
  {
    const unsigned short* kp = kF + (((b*2 + brh)*64 + w*8)*64 + lane)*8;
    #pragma unroll
    for (int i = 0; i < 8; i++) {
      s8v bf = *(const s8v*)(kp + i*512);
      f4v z4 = {0.f, 0.f, 0.f, 0.f};
      z4 = __builtin_amdgcn_mfma_f32_16x16x32_bf16(ql2, bf, z4, 0, 0, 0);
      acc[i] = __builtin_amdgcn_mfma_f32_16x16x32_bf16(qh1, bf, z4, 0, 0, 0);
    }
  }

  // ---- softmax (rows nl = g*4+r, this wave holds 128 m per row) ----
  float Mrow[4];
  #pragma unroll
  for (int r = 0; r < 4; r++) {
    float m = acc[0][r];
    #pragma unroll
    for (int i = 1; i < 8; i++) m = fmaxf(m, acc[i][r]);
    m = fmaxf(m, __shfl_xor(m, 1));
    m = fmaxf(m, __shfl_xor(m, 2));
    m = fmaxf(m, __shfl_xor(m, 4));
    m = fmaxf(m, __shfl_xor(m, 8));
    if (c16 == 0) smMax[(brh*8 + w)*16 + g*4 + r] = m;
  }
  __syncthreads();
  #pragma unroll
  for (int r = 0; r < 4; r++) {
    float m = smMax[(brh*8 + 0)*16 + g*4 + r];
    #pragma unroll
    for (int w2 = 1; w2 < 8; w2++) m = fmaxf(m, smMax[(brh*8 + w2)*16 + g*4 + r]);
    Mrow[r] = m;
  }
  float rsum[4] = {0.f, 0.f, 0.f, 0.f};
  #pragma unroll
  for (int i = 0; i < 8; i++) {
    #pragma unroll
    for (int r = 0; r < 4; r++) {
      float p = __expf(acc[i][r] - Mrow[r]);
      acc[i][r] = p;
      rsum[r] += p;
    }
  }
  #pragma unroll
  for (int r = 0; r < 4; r++) {
    float s = rsum[r];
    s += __shfl_xor(s, 1); s += __shfl_xor(s, 2);
    s += __shfl_xor(s, 4); s += __shfl_xor(s, 8);
    if (c16 == 0) smSum[(brh*8 + w)*16 + g*4 + r] = s;
  }
  __syncthreads();
  if (w == 0 && c16 == 0) {
    #pragma unroll
    for (int r = 0; r < 4; r++) {
      float s = 0.f;
      #pragma unroll
      for (int w2 = 0; w2 < 8; w2++) s += smSum[(brh*8 + w2)*16 + g*4 + r];
      invL[brh*16 + g*4 + r] = 1.0f / s;
    }
  }

  // ---- PV: per wave, 4 k-steps of 32 m; wave-local P transpose; 3-term split ----
  f4v z0 = {0.f,0.f,0.f,0.f}, z1 = z0, z2 = z0, z3 = z0;
  float* myPS = S + PS_OFF + wid*576;   // [16][36]
  #pragma unroll
  for (int ks4 = 0; ks4 < 4; ks4++) {
    #pragma unroll
    for (int i2 = 0; i2 < 2; i2++) {
      #pragma unroll
      for (int r = 0; r < 4; r++)
        myPS[(g*4 + r)*36 + i2*16 + c16] = acc[ks4*2 + i2][r];
    }
    float4 pa = *(const float4*)&myPS[c16*36 + g*8];
    float4 pb = *(const float4*)&myPS[c16*36 + g*8 + 4];
    s8v ph, pl;
    {
      unsigned short h0 = bf16r(pa.x); ph[0] = (short)h0; pl[0] = (short)bf16r(pa.x - bf16f(h0));
      unsigned short h1 = bf16r(pa.y); ph[1] = (short)h1; pl[1] = (short)bf16r(pa.y - bf16f(h1));
      unsigned short h2 = bf16r(pa.z); ph[2] = (short)h2; pl[2] = (short)bf16r(pa.z - bf16f(h2));
      unsigned short h3 = bf16r(pa.w); ph[3] = (short)h3; pl[3] = (short)bf16r(pa.w - bf16f(h3));
      unsigned short h4 = bf16r(pb.x); ph[4] = (short)h4; pl[4] = (short)bf16r(pb.x - bf16f(h4));
      unsigned short h5 = bf16r(pb.y); ph[5] = (short)h5; pl[5] = (short)bf16r(pb.y - bf16f(h5));
      unsigned short h6 = bf16r(pb.z); ph[6] = (short)h6; pl[6] = (short)bf16r(pb.z - bf16f(h6));
      unsigned short h7 = bf16r(pb.w); ph[7] = (short)h7; pl[7] = (short)bf16r(pb.w - bf16f(h7));
    }
    const int ks = w*4 + ks4;
    const unsigned short* vph = vFh + ((((b*2 + brh)*32 + ks)*4)*64 + lane)*8;
    const unsigned short* vpl = vFl + ((((b*2 + brh)*32 + ks)*4)*64 + lane)*8;
    s8v vh0 = *(const s8v*)(vph);
    s8v vl0 = *(const s8v*)(vpl);
    z0 = __builtin_amdgcn_mfma_f32_16x16x32_bf16(ph, vh0, z0, 0,0,0);
    z0 = __builtin_amdgcn_mfma_f32_16x16x32_bf16(ph, vl0, z0, 0,0,0);
    z0 = __builtin_amdgcn_mfma_f32_16x16x32_bf16(pl, vh0, z0, 0,0,0);
    s8v vh1 = *(const s8v*)(vph + 512);
    s8v vl1 = *(const s8v*)(vpl + 512);
    z1 = __builtin_amdgcn_mfma_f32_16x16x32_bf16(ph, vh1, z1, 0,0,0);
    z1 = __builtin_amdgcn_mfma_f32_16x16x32_bf16(ph, vl1, z1, 0,0,0);
    z1 = __builtin_amdgcn_mfma_f32_16x16x32_bf16(pl, vh1, z1, 0,0,0);
    s8v vh2 = *(const s8v*)(vph + 1024);
    s8v vl2 = *(const s8v*)(vpl + 1024);
    z2 = __builtin_amdgcn_mfma_f32_16x16x32_bf16(ph, vh2, z2, 0,0,0);
    z2 = __builtin_amdgcn_mfma_f32_16x16x32_bf16(ph, vl2, z2, 0,0,0);
    z2 = __builtin_amdgcn_mfma_f32_16x16x32_bf16(pl, vh2, z2, 0,0,0);
    s8v vh3 = *(const s8v*)(vph + 1536);
    s8v vl3 = *(const s8v*)(vpl + 1536);
    z3 = __builtin_amdgcn_mfma_f32_16x16x32_bf16(ph, vh3, z3, 0,0,0);
    z3 = __builtin_amdgcn_mfma_f32_16x16x32_bf16(ph, vl3, z3, 0,0,0);
    z3 = __builtin_amdgcn_mfma_f32_16x16x32_bf16(pl, vh3, z3, 0,0,0);
  }

  // ---- write partials, reduce 8 waves, normalize -> zhm ----
  {
    float* rw = red + wid*1056;
    #pragma unroll
    for (int r = 0; r < 4; r++) {
      rw[(g*4 + r)*66 +  0 + c16] = z0[r];
      rw[(g*4 + r)*66 + 16 + c16] = z1[r];
      rw[(g*4 + r)*66 + 32 + c16] = z2[r];
      rw[(g*4 + r)*66 + 48 + c16] = z3[r];
    }
  }
  __syncthreads();
  {
    const int br2 = tid >> 9;
    const int sub = tid & 511;
    const int nlr = sub >> 5;
    const int cc0 = (sub & 31) * 2;
    float iv = invL[br2*16 + nlr];
    #pragma unroll
    for (int u = 0; u < 2; u++) {
      int cc = cc0 + u;
      float s = 0.f;
      #pragma unroll
      for (int w2 = 0; w2 < 8; w2++)
        s += red[(br2*8 + w2)*1056 + nlr*66 + cc];
      zhm[(br2*64 + cc)*16 + nlr] = s * iv;
    }
  }
  __syncthreads();

  // ---- zz = z_w @ [zh; zm] + z_b  (+ stage hf rows); cbIn aliases red ----
  {
    const int oc  = tid & 127;
    const int nl0 = (tid >> 7) * 2;
    float s0 = z_b[oc], s1 = s0;
    for (int k = 0; k < 128; k++) {
      float ww = z_wT[k*128 + oc];
      float2 zz2 = *(const float2*)&zhm[k*16 + nl0];
      s0 = fmaf(ww, zz2.x, s0); s1 = fmaf(ww, zz2.y, s1);
    }
    cbIn[oc*16 + nl0]     = s0;
    cbIn[oc*16 + nl0 + 1] = s1;
    const int c = tid >> 4, nn = tid & 15;
    cbIn[(128 + c)*16 + nn] = h_nxt[(b*64 + c)*NN + n0 + nn];
  }
  __syncthreads();

  // ---- comb = m_w @ [zz; hf] + m_b ----
  if (tid < 768) {
    const int oc = tid >> 2;
    const int nl0 = (tid & 3) * 4;
    float4 a; a.x = a.y = a.z = a.w = m_b[oc];
    for (int k = 0; k < 192; k++) {
      float ww = m_wT[k*192 + oc];
      float4 v = *(const float4*)&cbIn[k*16 + nl0];
      a.x = fmaf(ww, v.x, a.x); a.y = fmaf(ww, v.y, a.y);
      a.z = fmaf(ww, v.z, a.z); a.w = fmaf(ww, v.w, a.w);
    }
    *(float4*)&cbOut[oc*16 + nl0] = a;
  }
  __syncthreads();

  // ---- gating ----
  {
    const int c = tid >> 4, nn = tid & 15;
    const int n = n0 + nn;
    float mo = cbOut[c*16 + nn];
    float mg = cbOut[(64 + c)*16 + nn];
    float mi = cbOut[(128 + c)*16 + nn];
    float mf = c_st[(b*64 + c)*NN + n];
    float mis = sigm(mi);
    float nmf = (1.0f - mis)*mf + mis*tanh_f(mg);
    float nhf = sigm(mo)*nmf;
    c_st[(b*64 + c)*NN + n] = nmf;
    h_nxt[(b*64 + c)*NN + n] = nhf;
    out[((b*64 + c)*SS + t)*NN + n] = nhf;
  }
}

extern "C" void kernel_launch(void* const* d_in, const int* in_sizes, int n_in,
                              void* d_out, int out_size, void* d_ws, size_t ws_size,
                              hipStream_t stream) {
  const float* X      = (const float*)d_in[0];
  const float* conv_w = (const float*)d_in[1];
  const float* conv_b = (const float*)d_in[2];
  const float* W_ci   = (const float*)d_in[3];
  const float* W_cf   = (const float*)d_in[4];
  const float* W_co   = (const float*)d_in[5];
  const float* qw  = (const float*)d_in[6];
  const float* qb  = (const float*)d_in[7];
  const float* kw  = (const float*)d_in[8];
  const float* kb  = (const float*)d_in[9];
  const float* k2w = (const float*)d_in[10];
  const float* k2b = (const float*)d_in[11];
  const float* vw  = (const float*)d_in[12];
  const float* vb  = (const float*)d_in[13];
  const float* v2w = (const float*)d_in[14];
  const float* v2b = (const float*)d_in[15];
  const float* z_w = (const float*)d_in[16];
  const float* z_b = (const float*)d_in[17];
  const float* m_w = (const float*)d_in[18];
  const float* m_b = (const float*)d_in[19];
  float* out = (float*)d_out;

  float* ws = (float*)d_ws;
  unsigned short* Whi = (unsigned short*)ws;  ws += 147456;   // 294912 ushorts
  unsigned short* Wlo = (unsigned short*)ws;  ws += 147456;
  float* z_wT   = ws;             ws += 128*128;
  float* m_wT   = ws;             ws += 192*192;
  float* h_A    = ws;             ws += NB*64*NN;
  float* h_B    = ws;             ws += NB*64*NN;
  float* c_st   = ws;             ws += NB*64*NN;
  float* q_buf  = ws;             ws += NB*16*NN;
  unsigned short* kF  = (unsigned short*)ws;  ws += 131072;   // 4b*2br*64mt*64*8 ushorts
  unsigned short* vFh = (unsigned short*)ws;  ws += 131072;   // 4b*2br*32ks*4nt*64*8
  unsigned short* vFl = (unsigned short*)ws;  ws += 131072;
  float* gx     = ws;             ws += NB*SS*256*NN;         // 16.8M floats, 67 MB

  hipLaunchKernelGGL(k0_prep, dim3(256), dim3(256), 0, stream,
                     conv_w, z_w, m_w, Whi, Wlo, z_wT, m_wT, h_A, c_st);
  hipLaunchKernelGGL(k0b_gx, dim3(1024), dim3(1024), 0, stream,
                     X, Whi, Wlo, gx);
  for (int t = 0; t < 16; t++) {
    const float* h_cur = (t & 1) ? h_B : h_A;
    float* h_nxt       = (t & 1) ? h_A : h_B;
    hipLaunchKernelGGL(k1_conv_lstm_proj, dim3(256), dim3(1024), 0, stream,
        t, gx, Whi, Wlo, conv_b, W_ci, W_cf, W_co,
        qw, qb, kw, kb, k2w, k2b, vw, vb, v2w, v2b,
        h_cur, h_nxt, c_st, q_buf, kF, vFh, vFl);
    hipLaunchKernelGGL(k2_attn, dim3(256), dim3(1024), 0, stream,
        t, q_buf, kF, vFh, vFl, h_nxt, c_st,
        z_wT, z_b, m_wT, m_b, out);
  }
}

// Round 10
// 751.786 us; speedup vs baseline: 1.0538x; 1.0538x over previous
//
#include <hip/hip_runtime.h>
#include <math.h>

#define NB 4
#define SS 16
#define NN 1024        // H*W

typedef short s8v __attribute__((ext_vector_type(8)));    // 8 bf16 (4 VGPR)
typedef float f4v __attribute__((ext_vector_type(4)));    // MFMA accumulator

__device__ __forceinline__ float sigm(float x) {
  return 1.0f / (1.0f + __expf(-x));
}
__device__ __forceinline__ float tanh_f(float x) {
  float e = __expf(2.0f * x);
  return 1.0f - 2.0f / (1.0f + e);
}
__device__ __forceinline__ unsigned short bf16r(float x) {   // RNE float->bf16
  unsigned int u = __float_as_uint(x);
  u = (u + 0x7FFFu + ((u >> 16) & 1u)) >> 16;
  return (unsigned short)u;
}
__device__ __forceinline__ float bf16f(unsigned short h) {
  return __uint_as_float(((unsigned int)h) << 16);
}

// ---------- prep: conv-weight split/pack + transposes + zero states ----------
__global__ void k0_prep(const float* __restrict__ conv_w, const float* __restrict__ z_w,
                        const float* __restrict__ m_w,
                        unsigned short* __restrict__ Whi, unsigned short* __restrict__ Wlo,
                        float* __restrict__ z_wT, float* __restrict__ m_wT,
                        float* __restrict__ h_A, float* __restrict__ c_st) {
  int stride = gridDim.x * blockDim.x;
  int i0 = blockIdx.x * blockDim.x + threadIdx.x;
  for (int i = i0; i < 256*1152; i += stride) {
    int oc = i / 1152, k = i - oc*1152;          // k = icComb*9 + ky*3 + kx
    float v = conv_w[i];
    unsigned short hi = bf16r(v);
    unsigned short lo = bf16r(v - bf16f(hi));
    int mt = oc >> 4, i16 = oc & 15;
    int ks = k >> 5, kk = k & 31;
    int lane = i16 | ((kk >> 3) << 4);
    int pos = ((mt*36 + ks)*64 + lane)*8 + (kk & 7);
    Whi[pos] = hi;
    Wlo[pos] = lo;
  }
  for (int i = i0; i < 128*128; i += stride) {
    int oc = i >> 7, k = i & 127;
    z_wT[k*128 + oc] = z_w[i];
  }
  for (int i = i0; i < 192*192; i += stride) {
    int oc = i / 192, k = i - oc*192;
    m_wT[k*192 + oc] = m_w[i];
  }
  for (int i = i0; i < NB*64*NN; i += stride) { h_A[i] = 0.0f; c_st[i] = 0.0f; }
}

// ---------- K0b (v1, reverted): conv_x for ALL (b,t) — parallel GEMM ----------
// block = (b, t, y): M=256, K=576 (ks 0..17 of Whi), N=32 (one row)
__global__ __launch_bounds__(1024, 2) void k0b_gx(
    const float* __restrict__ X,
    const unsigned short* __restrict__ Whi, const unsigned short* __restrict__ Wlo,
    float* __restrict__ gx)
{
  __shared__ __align__(16) unsigned short Xhi_l[18*2*64*8];   // [ks][nt][lane][8]
  __shared__ __align__(16) unsigned short Xlo_l[18*2*64*8];

  const int tid = threadIdx.x;
  const int bid = blockIdx.x;       // b*512 + t*32 + y
  const int y = bid & 31;
  const int t = (bid >> 5) & 15;
  const int b = bid >> 9;

  // im2col for one full row (32 outputs), x-channels only
  for (int idx = tid; idx < 64*3*34; idx += 1024) {
    int col = idx % 34;
    int rest = idx / 34;
    int dy = rest % 3;
    int ic = rest / 3;
    int gy = y + dy - 1;
    int gxc = col - 1;
    float v = 0.0f;
    if ((unsigned)gy < 32u && (unsigned)gxc < 32u)
      v = X[(((b*64 + ic)*SS + t)*NN) + gy*32 + gxc];
    unsigned short hi = bf16r(v);
    unsigned short lo = bf16r(v - bf16f(hi));
    int kbase = ic*9 + dy*3;
    #pragma unroll
    for (int dx = 0; dx < 3; dx++) {
      int n = col - dx;
      if ((unsigned)n < 32u) {
        int k = kbase + dx;
        int ks = k >> 5, kk = k & 31;
        int nt = n >> 4, n16 = n & 15;
        int pos = (((ks*2 + nt)*64) + (n16 | ((kk >> 3) << 4)))*8 + (kk & 7);
        Xhi_l[pos] = hi;
        Xlo_l[pos] = lo;
      }
    }
  }
  __syncthreads();

  const int lane = tid & 63;
  const int mt = tid >> 6;          // 0..15
  f4v acc0 = {0.f,0.f,0.f,0.f}, acc1 = acc0;
  const s8v* Ah = (const s8v*)Whi + (mt*36)*64 + lane;
  const s8v* Al = (const s8v*)Wlo + (mt*36)*64 + lane;
  const s8v* Bh = (const s8v*)Xhi_l + lane;
  const s8v* Bl = (const s8v*)Xlo_l + lane;
  #pragma unroll 3
  for (int ks = 0; ks < 18; ks++) {
    s8v ah  = Ah[ks*64];
    s8v al  = Al[ks*64];
    s8v bh0 = Bh[(ks*2 + 0)*64];
    s8v bl0 = Bl[(ks*2 + 0)*64];
    s8v bh1 = Bh[(ks*2 + 1)*64];
    s8v bl1 = Bl[(ks*2 + 1)*64];
    acc0 = __builtin_amdgcn_mfma_f32_16x16x32_bf16(ah, bh0, acc0, 0, 0, 0);
    acc0 = __builtin_amdgcn_mfma_f32_16x16x32_bf16(al, bh0, acc0, 0, 0, 0);
    acc0 = __builtin_amdgcn_mfma_f32_16x16x32_bf16(ah, bl0, acc0, 0, 0, 0);
    acc1 = __builtin_amdgcn_mfma_f32_16x16x32_bf16(ah, bh1, acc1, 0, 0, 0);
    acc1 = __builtin_amdgcn_mfma_f32_16x16x32_bf16(al, bh1, acc1, 0, 0, 0);
    acc1 = __builtin_amdgcn_mfma_f32_16x16x32_bf16(ah, bl1, acc1, 0, 0, 0);
  }
  const int c16 = lane & 15;
  const int rb  = (lane >> 4) * 4;
  float* gout = gx + (((long)b*SS + t)*256)*NN + y*32;
  #pragma unroll
  for (int r = 0; r < 4; r++) {
    gout[(mt*16 + rb + r)*NN + c16]      = acc0[r];
    gout[(mt*16 + rb + r)*NN + 16 + c16] = acc1[r];
  }
}

// ---------- K1: conv_h (MFMA split-bf16) + LSTM(+gx) + projections (1024 threads) ----------
__global__ __launch_bounds__(1024, 2) void k1_conv_lstm_proj(
    int t,
    const float* __restrict__ gx,
    const unsigned short* __restrict__ Whi, const unsigned short* __restrict__ Wlo,
    const float* __restrict__ conv_b,
    const float* __restrict__ W_ci, const float* __restrict__ W_cf, const float* __restrict__ W_co,
    const float* __restrict__ qw, const float* __restrict__ qb,
    const float* __restrict__ kw, const float* __restrict__ kb,
    const float* __restrict__ k2w, const float* __restrict__ k2b,
    const float* __restrict__ vw, const float* __restrict__ vb,
    const float* __restrict__ v2w, const float* __restrict__ v2b,
    const float* __restrict__ h_cur, float* __restrict__ h_nxt,
    float* __restrict__ c_st,
    float* __restrict__ q_buf,
    unsigned short* __restrict__ kF,
    unsigned short* __restrict__ vFh, unsigned short* __restrict__ vFl)
{
  __shared__ __align__(16) unsigned short Ihi_l[18*64*8];      // h-only im2col, B-frag order
  __shared__ __align__(16) unsigned short Ilo_l[18*64*8];
  __shared__ __align__(16) float gates_l[256*17];              // [oc][x]; later proj_l[176][16]
  __shared__ __align__(16) float h_l[16*68];                   // [x][c]
  __shared__ __align__(16) float c_l[16*68];
  __shared__ __align__(16) float pw_l[176*68];                 // proj weights staged in LDS
  __shared__ __align__(16) float pb_l[176];

  const int tid = threadIdx.x;
  const int bid = blockIdx.x;
  const int b  = bid >> 6;
  const int y  = (bid >> 1) & 31;
  const int x0 = (bid & 1) * 16;
  const int mt = bid & 63;          // this block's 16-col m-tile (= n>>4)
  const int n0 = y*32 + x0;

  // ---- prefetch LSTM inputs into registers (latency hides under im2col+MFMA) ----
  const int px = tid & 15;
  const int pc = tid >> 4;          // 0..63
  const int pn = n0 + px;
  const float* gxp = gx + (((long)b*SS + t)*256)*NN + pn;
  float pf_g0 = gxp[(pc      )*NN];
  float pf_g1 = gxp[( 64 + pc)*NN];
  float pf_g2 = gxp[(128 + pc)*NN];
  float pf_g3 = gxp[(192 + pc)*NN];
  float pf_cp  = c_st[(b*64 + pc)*NN + pn];
  float pf_wci = W_ci[pc*NN + pn];
  float pf_wcf = W_cf[pc*NN + pn];
  float pf_wco = W_co[pc*NN + pn];
  float pf_b0 = conv_b[pc];
  float pf_b1 = conv_b[ 64 + pc];
  float pf_b2 = conv_b[128 + pc];
  float pf_b3 = conv_b[192 + pc];

  // ---- phase 0: h-only im2col -> B-frags  +  stage proj weights into LDS ----
  for (int idx = tid; idx < 64*3*18; idx += 1024) {
    int col = idx % 18;
    int rest = idx / 18;
    int dy = rest % 3;
    int ic = rest / 3;                    // h channel 0..63
    int gy = y + dy - 1;
    int gxc = x0 + col - 1;
    float v = 0.0f;
    if ((unsigned)gy < 32u && (unsigned)gxc < 32u)
      v = h_cur[((b*64 + ic)*NN) + gy*32 + gxc];
    unsigned short hi = bf16r(v);
    unsigned short lo = bf16r(v - bf16f(hi));
    int kbase = ic*9 + dy*3;              // local k in [0,576)
    #pragma unroll
    for (int dx = 0; dx < 3; dx++) {
      int n = col - dx;
      if ((unsigned)n < 16u) {
        int k = kbase + dx;
        int ks = k >> 5, kk = k & 31;
        int pos = (ks*64 + (n | ((kk >> 3) << 4)))*8 + (kk & 7);
        Ihi_l[pos] = hi;
        Ilo_l[pos] = lo;
      }
    }
  }
  for (int idx = tid; idx < 176*64; idx += 1024) {
    int po = idx >> 6, c = idx & 63;
    float v;
    if (po < 16)       v = qw[po*64 + c];
    else if (po < 32)  v = kw[(po-16)*64 + c];
    else if (po < 96)  v = vw[(po-32)*64 + c];
    else if (po < 112) v = k2w[(po-96)*64 + c];
    else               v = v2w[(po-112)*64 + c];
    pw_l[po*68 + c] = v;
  }
  if (tid < 176) {
    int po = tid;
    float v;
    if (po < 16)       v = qb[po];
    else if (po < 32)  v = kb[po-16];
    else if (po < 96)  v = vb[po-32];
    else if (po < 112) v = k2b[po-96];
    else               v = v2b[po-112];
    pb_l[po] = v;
  }
  __syncthreads();

  // ---- phase 1: conv_h MFMA: 16 waves, 1 m-tile each; A-frags at ks 18..35 ----
  {
    const int lane = tid & 63;
    const int wv   = tid >> 6;        // 0..15 = m-tile
    f4v acc = {0.f, 0.f, 0.f, 0.f};
    const s8v* Ah = (const s8v*)Whi + (wv*36 + 18)*64 + lane;
    const s8v* Al = (const s8v*)Wlo + (wv*36 + 18)*64 + lane;
    const s8v* Bh = (const s8v*)Ihi_l + lane;
    const s8v* Bl = (const s8v*)Ilo_l + lane;
    #pragma unroll 3
    for (int ks = 0; ks < 18; ks++) {
      s8v ah = Ah[ks*64];
      s8v al = Al[ks*64];
      s8v bh = Bh[ks*64];
      s8v bl = Bl[ks*64];
      acc = __builtin_amdgcn_mfma_f32_16x16x32_bf16(ah, bh, acc, 0, 0, 0);
      acc = __builtin_amdgcn_mfma_f32_16x16x32_bf16(al, bh, acc, 0, 0, 0);
      acc = __builtin_amdgcn_mfma_f32_16x16x32_bf16(ah, bl, acc, 0, 0, 0);
    }
    const int colx = lane & 15;
    const int rb   = (lane >> 4) * 4;
    #pragma unroll
    for (int r = 0; r < 4; r++)
      gates_l[(wv*16 + rb + r)*17 + colx] = acc[r];
  }
  __syncthreads();

  // ---- phase 2: LSTM elementwise (prefetched inputs) ----
  {
    const int x = px;
    const int c = pc;
    const int n = pn;
    float ig = gates_l[(c      )*17 + x] + pf_g0 + pf_b0;
    float fg = gates_l[( 64 + c)*17 + x] + pf_g1 + pf_b1;
    float gg = gates_l[(128 + c)*17 + x] + pf_g2 + pf_b2;
    float og = gates_l[(192 + c)*17 + x] + pf_g3 + pf_b3;
    float cp = pf_cp;
    float i_ = sigm(ig + pf_wci * cp);
    float f_ = sigm(fg + pf_wcf * cp);
    float cn = f_*cp + i_*tanh_f(gg);
    float o_ = sigm(og + pf_wco * cn);
    float hn = o_*tanh_f(cn);
    h_nxt[(b*64 + c)*NN + n] = hn;
    c_st[(b*64 + c)*NN + n] = cn;
    h_l[x*68 + c] = hn;
    c_l[x*68 + c] = cn;
  }
  __syncthreads();

  // ---- phase 3: projections (weights from LDS) -> LDS staging ----
  float* proj_l = gates_l;
  #pragma unroll
  for (int r0 = 0; r0 < 3; r0++) {
    int task = tid + r0*1024;
    if (task < 176*16) {
      int po = task >> 4, x = task & 15;
      const float* src = (po < 96) ? &h_l[x*68] : &c_l[x*68];
      const float* w = &pw_l[po*68];
      float s = pb_l[po];
      #pragma unroll
      for (int k = 0; k < 64; k += 4) {
        float4 wv = *(const float4*)&w[k];
        float4 sv = *(const float4*)&src[k];
        s = fmaf(wv.x, sv.x, s); s = fmaf(wv.y, sv.y, s);
        s = fmaf(wv.z, sv.z, s); s = fmaf(wv.w, sv.w, s);
      }
      proj_l[po*16 + x] = s;
    }
  }
  __syncthreads();

  // ---- phase 4: coalesced fragment emission ----
  if (tid < 256) {
    int d = tid >> 4, x = tid & 15;
    q_buf[(b*16 + d)*NN + n0 + x] = proj_l[d*16 + x];
  }
  if (tid < 512) {
    int brh2 = tid >> 8;            // branch
    int lh   = (tid >> 2) & 63;     // fragment "lane-half" row
    int j2   = tid & 3;             // packs d&7 = 2*j2, 2*j2+1
    int p    = lh >> 4;             // 0,1: hi planes; 2,3: lo planes
    int x    = lh & 15;
    int d0   = ((p & 1) << 3) | (j2 << 1);
    int Koff = brh2 ? 96 : 16;
    float v0 = proj_l[(Koff + d0)*16 + x];
    float v1 = proj_l[(Koff + d0 + 1)*16 + x];
    unsigned short h0 = bf16r(v0), h1 = bf16r(v1);
    unsigned short u0, u1;
    if (p < 2) { u0 = h0; u1 = h1; }
    else       { u0 = bf16r(v0 - bf16f(h0)); u1 = bf16r(v1 - bf16f(h1)); }
    unsigned int* dst = (unsigned int*)(kF + ((b*2 + brh2)*64 + mt)*512);
    dst[lh*4 + j2] = (unsigned)u0 | ((unsigned)u1 << 16);
  }
  {
    const int ks = y;
    const int g0 = x0 >> 3;         // 0 or 2
    #pragma unroll
    for (int it = 0; it < 2; it++) {
      int ct    = tid + it*1024;
      int plane = ct >> 10;         // 0 = vFh, 1 = vFl
      int brh2  = (ct >> 9) & 1;
      int nt    = (ct >> 7) & 3;
      int li    = (ct >> 2) & 31;
      int j2    = ct & 3;
      int lane2 = g0*16 + li;
      int cch   = nt*16 + (lane2 & 15);
      int xx    = ((li >> 4) << 3) | (j2 << 1);
      int Voff  = brh2 ? 112 : 32;
      float v0 = proj_l[(Voff + cch)*16 + xx];
      float v1 = proj_l[(Voff + cch)*16 + xx + 1];
      unsigned short h0 = bf16r(v0), h1 = bf16r(v1);
      unsigned short u0, u1;
      if (plane == 0) { u0 = h0; u1 = h1; }
      else            { u0 = bf16r(v0 - bf16f(h0)); u1 = bf16r(v1 - bf16f(h1)); }
      unsigned short* basep = (plane ? vFl : vFh) + (((b*2 + brh2)*32 + ks)*4 + nt)*512;
      ((unsigned int*)basep)[lane2*4 + j2] = (unsigned)u0 | ((unsigned)u1 << 16);
    }
  }
}

// ---------- K2: dual attention via MFMA + combine + gating ----------
#define RED_OFF 0        // [16 waves][16 nl][66]  = 16896
#define PS_OFF  16896    // [16 waves][16][36]     = 9216
#define SMX_OFF 26112    // [2][8][16]             = 256
#define SSM_OFF 26368    // [2][8][16]             = 256
#define INV_OFF 26624    // [2][16]                = 32
#define ZHM_OFF 26656    // [128][16]              = 2048
#define S_TOT   28704

__global__ __launch_bounds__(1024, 4) void k2_attn(
    int t,
    const float* __restrict__ q_buf,
    const unsigned short* __restrict__ kF,
    const unsigned short* __restrict__ vFh, const unsigned short* __restrict__ vFl,
    float* __restrict__ h_nxt, float* __restrict__ c_st,
    const float* __restrict__ z_wT, const float* __restrict__ z_b,
    const float* __restrict__ m_wT, const float* __restrict__ m_b,
    float* __restrict__ out)
{
  __shared__ __align__(16) float S[S_TOT];
  float* red  = S + RED_OFF;
  float* smMax= S + SMX_OFF;
  float* smSum= S + SSM_OFF;
  float* invL = S + INV_OFF;
  float* zhm  = S + ZHM_OFF;
  float* cbIn = S;              // alias red (after barrier)
  float* cbOut= S + 3072;       // alias red

  const int tid = threadIdx.x;
  const int bid = blockIdx.x;
  const int xcd = bid & 7;
  const int b = xcd >> 1;
  const int tile = ((bid >> 3) << 1) | (xcd & 1);   // 0..63
  const int n0 = tile * 16;

  const int wid  = tid >> 6;
  const int lane = tid & 63;
  const int brh  = wid >> 3;      // branch
  const int w    = wid & 7;       // wave within branch
  const int g    = lane >> 4;
  const int c16  = lane & 15;

  // ---- prefetch tail-phase inputs (latency hides under attention) ----
  const int pc2 = tid >> 4;       // 0..63
  const int pn2 = n0 + (tid & 15);
  float pf_cst = c_st[(b*64 + pc2)*NN + pn2];
  float pf_h   = h_nxt[(b*64 + pc2)*NN + pn2];

  // ---- Q A-frags: A1 = [Qh|Qh], A2 = [Ql|0] ----
  s8v qh1, ql2;
  {
    const int dbase = (g & 1) * 8;
    #pragma unroll
    for (int j = 0; j < 8; j++) {
      float qv = q_buf[(b*16 + dbase + j)*NN + n0 + c16];
      unsigned short hi = bf16r(qv);
      unsigned short lo = bf16r(qv - bf16f(hi));
      qh1[j] = (short)hi;
      ql2[j] = (g < 2) ? (short)lo : (short)0;
    }
  }

  // ---- scores: 8 m-tiles per wave, 2 MFMA each (B = [Kh|Kl]) ----
  f4v acc[8];
  {
    const unsigned short* kp = kF + (((b*2 + brh)*64 + w*8)*64 + lane)*8;
    #pragma unroll
    for (int i = 0; i < 8; i++) {
      s8v bf = *(const s8v*)(kp + i*512);
      f4v z4 = {0.f, 0.f, 0.f, 0.f};
      z4 = __builtin_amdgcn_mfma_f32_16x16x32_bf16(ql2, bf, z4, 0, 0, 0);
      acc[i] = __builtin_amdgcn_mfma_f32_16x16x32_bf16(qh1, bf, z4, 0, 0, 0);
    }
  }

  // ---- softmax (rows nl = g*4+r, this wave holds 128 m per row) ----
  float Mrow[4];
  #pragma unroll
  for (int r = 0; r < 4; r++) {
    float m = acc[0][r];
    #pragma unroll
    for (int i = 1; i < 8; i++) m = fmaxf(m, acc[i][r]);
    m = fmaxf(m, __shfl_xor(m, 1));
    m = fmaxf(m, __shfl_xor(m, 2));
    m = fmaxf(m, __shfl_xor(m, 4));
    m = fmaxf(m, __shfl_xor(m, 8));
    if (c16 == 0) smMax[(brh*8 + w)*16 + g*4 + r] = m;
  }
  __syncthreads();
  #pragma unroll
  for (int r = 0; r < 4; r++) {
    float m = smMax[(brh*8 + 0)*16 + g*4 + r];
    #pragma unroll
    for (int w2 = 1; w2 < 8; w2++) m = fmaxf(m, smMax[(brh*8 + w2)*16 + g*4 + r]);
    Mrow[r] = m;
  }
  float rsum[4] = {0.f, 0.f, 0.f, 0.f};
  #pragma unroll
  for (int i = 0; i < 8; i++) {
    #pragma unroll
    for (int r = 0; r < 4; r++) {
      float p = __expf(acc[i][r] - Mrow[r]);
      acc[i][r] = p;
      rsum[r] += p;
    }
  }
  #pragma unroll
  for (int r = 0; r < 4; r++) {
    float s = rsum[r];
    s += __shfl_xor(s, 1); s += __shfl_xor(s, 2);
    s += __shfl_xor(s, 4); s += __shfl_xor(s, 8);
    if (c16 == 0) smSum[(brh*8 + w)*16 + g*4 + r] = s;
  }
  __syncthreads();
  if (w == 0 && c16 == 0) {
    #pragma unroll
    for (int r = 0; r < 4; r++) {
      float s = 0.f;
      #pragma unroll
      for (int w2 = 0; w2 < 8; w2++) s += smSum[(brh*8 + w2)*16 + g*4 + r];
      invL[brh*16 + g*4 + r] = 1.0f / s;
    }
  }

  // ---- PV: per wave, 4 k-steps of 32 m; wave-local P transpose; 3-term split ----
  f4v z0 = {0.f,0.f,0.f,0.f}, z1 = z0, z2 = z0, z3 = z0;
  float* myPS = S + PS_OFF + wid*576;   // [16][36]
  #pragma unroll
  for (int ks4 = 0; ks4 < 4; ks4++) {
    #pragma unroll
    for (int i2 = 0; i2 < 2; i2++) {
      #pragma unroll
      for (int r = 0; r < 4; r++)
        myPS[(g*4 + r)*36 + i2*16 + c16] = acc[ks4*2 + i2][r];
    }
    float4 pa = *(const float4*)&myPS[c16*36 + g*8];
    float4 pb = *(const float4*)&myPS[c16*36 + g*8 + 4];
    s8v ph, pl;
    {
      unsigned short h0 = bf16r(pa.x); ph[0] = (short)h0; pl[0] = (short)bf16r(pa.x - bf16f(h0));
      unsigned short h1 = bf16r(pa.y); ph[1] = (short)h1; pl[1] = (short)bf16r(pa.y - bf16f(h1));
      unsigned short h2 = bf16r(pa.z); ph[2] = (short)h2; pl[2] = (short)bf16r(pa.z - bf16f(h2));
      unsigned short h3 = bf16r(pa.w); ph[3] = (short)h3; pl[3] = (short)bf16r(pa.w - bf16f(h3));
      unsigned short h4 = bf16r(pb.x); ph[4] = (short)h4; pl[4] = (short)bf16r(pb.x - bf16f(h4));
      unsigned short h5 = bf16r(pb.y); ph[5] = (short)h5; pl[5] = (short)bf16r(pb.y - bf16f(h5));
      unsigned short h6 = bf16r(pb.z); ph[6] = (short)h6; pl[6] = (short)bf16r(pb.z - bf16f(h6));
      unsigned short h7 = bf16r(pb.w); ph[7] = (short)h7; pl[7] = (short)bf16r(pb.w - bf16f(h7));
    }
    const int ks = w*4 + ks4;
    const unsigned short* vph = vFh + ((((b*2 + brh)*32 + ks)*4)*64 + lane)*8;
    const unsigned short* vpl = vFl + ((((b*2 + brh)*32 + ks)*4)*64 + lane)*8;
    s8v vh0 = *(const s8v*)(vph);
    s8v vl0 = *(const s8v*)(vpl);
    z0 = __builtin_amdgcn_mfma_f32_16x16x32_bf16(ph, vh0, z0, 0,0,0);
    z0 = __builtin_amdgcn_mfma_f32_16x16x32_bf16(ph, vl0, z0, 0,0,0);
    z0 = __builtin_amdgcn_mfma_f32_16x16x32_bf16(pl, vh0, z0, 0,0,0);
    s8v vh1 = *(const s8v*)(vph + 512);
    s8v vl1 = *(const s8v*)(vpl + 512);
    z1 = __builtin_amdgcn_mfma_f32_16x16x32_bf16(ph, vh1, z1, 0,0,0);
    z1 = __builtin_amdgcn_mfma_f32_16x16x32_bf16(ph, vl1, z1, 0,0,0);
    z1 = __builtin_amdgcn_mfma_f32_16x16x32_bf16(pl, vh1, z1, 0,0,0);
    s8v vh2 = *(const s8v*)(vph + 1024);
    s8v vl2 = *(const s8v*)(vpl + 1024);
    z2 = __builtin_amdgcn_mfma_f32_16x16x32_bf16(ph, vh2, z2, 0,0,0);
    z2 = __builtin_amdgcn_mfma_f32_16x16x32_bf16(ph, vl2, z2, 0,0,0);
    z2 = __builtin_amdgcn_mfma_f32_16x16x32_bf16(pl, vh2, z2, 0,0,0);
    s8v vh3 = *(const s8v*)(vph + 1536);
    s8v vl3 = *(const s8v*)(vpl + 1536);
    z3 = __builtin_amdgcn_mfma_f32_16x16x32_bf16(ph, vh3, z3, 0,0,0);
    z3 = __builtin_amdgcn_mfma_f32_16x16x32_bf16(ph, vl3, z3, 0,0,0);
    z3 = __builtin_amdgcn_mfma_f32_16x16x32_bf16(pl, vh3, z3, 0,0,0);
  }

  // ---- write partials, reduce 8 waves, normalize -> zhm ----
  {
    float* rw = red + wid*1056;
    #pragma unroll
    for (int r = 0; r < 4; r++) {
      rw[(g*4 + r)*66 +  0 + c16] = z0[r];
      rw[(g*4 + r)*66 + 16 + c16] = z1[r];
      rw[(g*4 + r)*66 + 32 + c16] = z2[r];
      rw[(g*4 + r)*66 + 48 + c16] = z3[r];
    }
  }
  __syncthreads();
  {
    const int br2 = tid >> 9;
    const int sub = tid & 511;
    const int nlr = sub >> 5;
    const int cc0 = (sub & 31) * 2;
    float iv = invL[br2*16 + nlr];
    #pragma unroll
    for (int u = 0; u < 2; u++) {
      int cc = cc0 + u;
      float s = 0.f;
      #pragma unroll
      for (int w2 = 0; w2 < 8; w2++)
        s += red[(br2*8 + w2)*1056 + nlr*66 + cc];
      zhm[(br2*64 + cc)*16 + nlr] = s * iv;
    }
  }
  __syncthreads();

  // ---- zz = z_w @ [zh; zm] + z_b  (+ stage hf rows); cbIn aliases red ----
  {
    const int oc  = tid & 127;
    const int nl0 = (tid >> 7) * 2;
    float s0 = z_b[oc], s1 = s0;
    for (int k = 0; k < 128; k++) {
      float ww = z_wT[k*128 + oc];
      float2 zz2 = *(const float2*)&zhm[k*16 + nl0];
      s0 = fmaf(ww, zz2.x, s0); s1 = fmaf(ww, zz2.y, s1);
    }
    cbIn[oc*16 + nl0]     = s0;
    cbIn[oc*16 + nl0 + 1] = s1;
    cbIn[(128 + pc2)*16 + (tid & 15)] = pf_h;
  }
  __syncthreads();

  // ---- comb = m_w @ [zz; hf] + m_b ----
  if (tid < 768) {
    const int oc = tid >> 2;
    const int nl0 = (tid & 3) * 4;
    float4 a; a.x = a.y = a.z = a.w = m_b[oc];
    for (int k = 0; k < 192; k++) {
      float ww = m_wT[k*192 + oc];
      float4 v = *(const float4*)&cbIn[k*16 + nl0];
      a.x = fmaf(ww, v.x, a.x); a.y = fmaf(ww, v.y, a.y);
      a.z = fmaf(ww, v.z, a.z); a.w = fmaf(ww, v.w, a.w);
    }
    *(float4*)&cbOut[oc*16 + nl0] = a;
  }
  __syncthreads();

  // ---- gating ----
  {
    const int c = pc2, nn = tid & 15;
    const int n = n0 + nn;
    float mo = cbOut[c*16 + nn];
    float mg = cbOut[(64 + c)*16 + nn];
    float mi = cbOut[(128 + c)*16 + nn];
    float mf = pf_cst;
    float mis = sigm(mi);
    float nmf = (1.0f - mis)*mf + mis*tanh_f(mg);
    float nhf = sigm(mo)*nmf;
    c_st[(b*64 + c)*NN + n] = nmf;
    h_nxt[(b*64 + c)*NN + n] = nhf;
    out[((b*64 + c)*SS + t)*NN + n] = nhf;
  }
}

extern "C" void kernel_launch(void* const* d_in, const int* in_sizes, int n_in,
                              void* d_out, int out_size, void* d_ws, size_t ws_size,
                              hipStream_t stream) {
  const float* X      = (const float*)d_in[0];
  const float* conv_w = (const float*)d_in[1];
  const float* conv_b = (const float*)d_in[2];
  const float* W_ci   = (const float*)d_in[3];
  const float* W_cf   = (const float*)d_in[4];
  const float* W_co   = (const float*)d_in[5];
  const float* qw  = (const float*)d_in[6];
  const float* qb  = (const float*)d_in[7];
  const float* kw  = (const float*)d_in[8];
  const float* kb  = (const float*)d_in[9];
  const float* k2w = (const float*)d_in[10];
  const float* k2b = (const float*)d_in[11];
  const float* vw  = (const float*)d_in[12];
  const float* vb  = (const float*)d_in[13];
  const float* v2w = (const float*)d_in[14];
  const float* v2b = (const float*)d_in[15];
  const float* z_w = (const float*)d_in[16];
  const float* z_b = (const float*)d_in[17];
  const float* m_w = (const float*)d_in[18];
  const float* m_b = (const float*)d_in[19];
  float* out = (float*)d_out;

  float* ws = (float*)d_ws;
  unsigned short* Whi = (unsigned short*)ws;  ws += 147456;   // 294912 ushorts
  unsigned short* Wlo = (unsigned short*)ws;  ws += 147456;
  float* z_wT   = ws;             ws += 128*128;
  float* m_wT   = ws;             ws += 192*192;
  float* h_A    = ws;             ws += NB*64*NN;
  float* h_B    = ws;             ws += NB*64*NN;
  float* c_st   = ws;             ws += NB*64*NN;
  float* q_buf  = ws;             ws += NB*16*NN;
  unsigned short* kF  = (unsigned short*)ws;  ws += 131072;   // 4b*2br*64mt*64*8 ushorts
  unsigned short* vFh = (unsigned short*)ws;  ws += 131072;   // 4b*2br*32ks*4nt*64*8
  unsigned short* vFl = (unsigned short*)ws;  ws += 131072;
  float* gx     = ws;             ws += NB*SS*256*NN;         // 16.8M floats, 67 MB

  hipLaunchKernelGGL(k0_prep, dim3(256), dim3(256), 0, stream,
                     conv_w, z_w, m_w, Whi, Wlo, z_wT, m_wT, h_A, c_st);
  hipLaunchKernelGGL(k0b_gx, dim3(2048), dim3(1024), 0, stream,
                     X, Whi, Wlo, gx);
  for (int t = 0; t < 16; t++) {
    const float* h_cur = (t & 1) ? h_B : h_A;
    float* h_nxt       = (t & 1) ? h_A : h_B;
    hipLaunchKernelGGL(k1_conv_lstm_proj, dim3(256), dim3(1024), 0, stream,
        t, gx, Whi, Wlo, conv_b, W_ci, W_cf, W_co,
        qw, qb, kw, kb, k2w, k2b, vw, vb, v2w, v2b,
        h_cur, h_nxt, c_st, q_buf, kF, vFh, vFl);
    hipLaunchKernelGGL(k2_attn, dim3(256), dim3(1024), 0, stream,
        t, q_buf, kF, vFh, vFl, h_nxt, c_st,
        z_wT, z_b, m_wT, m_b, out);
  }
}